// Round 3
// baseline (11673.225 us; speedup 1.0000x reference)
//
#include <hip/hip_runtime.h>

// T=64, B=64, S=64, E=1024, D=1024, L=2
// Persistent kernel, 256 blocks x 256 threads, 4 flag-array grid barriers/step:
//   A : gates0 = xA[p]([feed|emb_t|h0prev], K=3072)·Wg0q^T -> pointwise -> h_0
//   B : gates1 = xB[p]([h_0|h1prev], K=2048)·Wg1q^T -> pointwise -> h1
//   C : scores=h1f·ctx2, softmax -> align (blocks 0-63) | qh=h1·WoutH^T (64-127)
//   D : attn_h = tanh(qh + sum_s align*ctx3[s,b,:]) ; stage xA[1-p]
// Weight rows gate-interleaved (row = d*4 + gate) so each block's 16 GEMM
// columns contain all 4 gates of 4 d-values -> block-local LSTM pointwise,
// and every weight row is fetched exactly ONCE per step chip-wide.

typedef __attribute__((ext_vector_type(8))) short bf16x8;
typedef __attribute__((ext_vector_type(4))) float f32x4;
typedef unsigned short u16;

__device__ __forceinline__ float bf2f(u16 u) {
  return __uint_as_float(((unsigned int)u) << 16);
}
__device__ __forceinline__ u16 f2bf(float f) {
  unsigned int u = __float_as_uint(f);
  u += 0x7FFFu + ((u >> 16) & 1u);
  return (u16)(u >> 16);
}
__device__ __forceinline__ float sigmoidf_(float x) { return 1.0f / (1.0f + expf(-x)); }

// ---------------- one-time: pack weights/context to bf16, bias sums --------
__global__ __launch_bounds__(256) void k_prep(
    const float* __restrict__ Wih0, const float* __restrict__ Whh0,
    const float* __restrict__ Wih1, const float* __restrict__ Whh1,
    const float* __restrict__ Wout, const float* __restrict__ Win,
    const float* __restrict__ ctx,
    const float* __restrict__ bih0, const float* __restrict__ bhh0,
    const float* __restrict__ bih1, const float* __restrict__ bhh1,
    u16* __restrict__ Wg0q, u16* __restrict__ Wg1q,
    u16* __restrict__ WoutCb, u16* __restrict__ WoutHb,
    u16* __restrict__ WinT, u16* __restrict__ ctxb,
    float* __restrict__ b0q, float* __restrict__ b1q)
{
  long i = (long)blockIdx.x * 256 + threadIdx.x;
  const long N0 = 4096L * 3072, N1 = 4096L * 2048, NM = 1024L * 1024,
             NC = 4194304L;
  if (i < N0) {  // Wg0q row r=d*4+g : [Wih0_feed | Wih0_emb | Whh0]
    long r = i / 3072, k = i % 3072;
    long d = r >> 2, g = r & 3;
    long row = g * 1024 + d;
    float v = (k < 1024) ? Wih0[row * 2048 + 1024 + k]
            : (k < 2048) ? Wih0[row * 2048 + (k - 1024)]
                         : Whh0[row * 1024 + (k - 2048)];
    Wg0q[i] = f2bf(v); return;
  }
  i -= N0;
  if (i < N1) {  // Wg1q row r=d*4+g : [Wih1 | Whh1]
    long r = i / 2048, k = i % 2048;
    long d = r >> 2, g = r & 3;
    long row = g * 1024 + d;
    float v = (k < 1024) ? Wih1[row * 1024 + k] : Whh1[row * 1024 + (k - 1024)];
    Wg1q[i] = f2bf(v); return;
  }
  i -= N1;
  if (i < NM) { long d = i >> 10, e = i & 1023; WoutCb[i] = f2bf(Wout[d * 2048 + e]); return; }
  i -= NM;
  if (i < NM) { long d = i >> 10, e = i & 1023; WoutHb[i] = f2bf(Wout[d * 2048 + 1024 + e]); return; }
  i -= NM;
  if (i < NM) { long e = i >> 10, d = i & 1023; WinT[i] = f2bf(Win[d * 1024 + e]); return; }
  i -= NM;
  if (i < NC) { ctxb[i] = f2bf(ctx[i]); return; }
  i -= NC;
  if (i < 4096) {  // b0q[d*4+g]
    long d = i >> 2, g = i & 3;
    b0q[i] = bih0[g * 1024 + d] + bhh0[g * 1024 + d]; return;
  }
  i -= 4096;
  if (i < 4096) {
    long d = i >> 2, g = i & 3;
    b1q[i] = bih1[g * 1024 + d] + bhh1[g * 1024 + d];
  }
}

// ---------------- one-time: C[m][n] = sum_k A[m][k]*B[n][k], M=4096,N=1024,K=1024
__global__ __launch_bounds__(256) void k_gemm1k(
    const u16* __restrict__ A, const u16* __restrict__ Bm, u16* __restrict__ Cm)
{
  const int lane = threadIdx.x & 63, wv = threadIdx.x >> 6;
  const int quad = lane >> 4, cL = lane & 15;
  const int n0 = blockIdx.x * 64;
  const int m0 = blockIdx.y * 64 + wv * 16;
  f32x4 a0 = {0,0,0,0}, a1 = {0,0,0,0}, a2 = {0,0,0,0}, a3 = {0,0,0,0};
  const u16* ap  = A  + (size_t)(m0 + cL) * 1024 + quad * 8;
  const u16* bp0 = Bm + (size_t)(n0 +  0 + cL) * 1024 + quad * 8;
  const u16* bp1 = Bm + (size_t)(n0 + 16 + cL) * 1024 + quad * 8;
  const u16* bp2 = Bm + (size_t)(n0 + 32 + cL) * 1024 + quad * 8;
  const u16* bp3 = Bm + (size_t)(n0 + 48 + cL) * 1024 + quad * 8;
  #pragma unroll 4
  for (int kc = 0; kc < 1024; kc += 32) {
    bf16x8 a  = *(const bf16x8*)ap;  ap  += 32;
    bf16x8 b0 = *(const bf16x8*)bp0; bp0 += 32;
    bf16x8 b1 = *(const bf16x8*)bp1; bp1 += 32;
    bf16x8 b2 = *(const bf16x8*)bp2; bp2 += 32;
    bf16x8 b3 = *(const bf16x8*)bp3; bp3 += 32;
    a0 = __builtin_amdgcn_mfma_f32_16x16x32_bf16(a, b0, a0, 0, 0, 0);
    a1 = __builtin_amdgcn_mfma_f32_16x16x32_bf16(a, b1, a1, 0, 0, 0);
    a2 = __builtin_amdgcn_mfma_f32_16x16x32_bf16(a, b2, a2, 0, 0, 0);
    a3 = __builtin_amdgcn_mfma_f32_16x16x32_bf16(a, b3, a3, 0, 0, 0);
  }
  #pragma unroll
  for (int r = 0; r < 4; ++r) {
    size_t base = (size_t)(m0 + quad * 4 + r) * 1024;
    Cm[base + n0 +  0 + cL] = f2bf(a0[r]);
    Cm[base + n0 + 16 + cL] = f2bf(a1[r]);
    Cm[base + n0 + 32 + cL] = f2bf(a2[r]);
    Cm[base + n0 + 48 + cL] = f2bf(a3[r]);
  }
}

// ---------------- one-time: initial state + barrier reset ------------------
__global__ __launch_bounds__(256) void k_init(
    const float* __restrict__ emb, const float* __restrict__ feed0,
    const float* __restrict__ h0, const float* __restrict__ c0,
    u16* __restrict__ xA, u16* __restrict__ xB1, float* __restrict__ cst,
    unsigned int* __restrict__ bar)
{
  int i = blockIdx.x * 256 + threadIdx.x;
  if (i < 196608) {  // xA[par0] = [feed | emb_0 | h0_layer0]
    int b = i / 3072, k = i % 3072;
    float v = (k < 1024) ? feed0[b * 1024 + k]
            : (k < 2048) ? emb[b * 1024 + (k - 1024)]
                         : h0[b * 1024 + (k - 2048)];
    xA[i] = f2bf(v); return;
  }
  i -= 196608;
  if (i < 65536) {  // xB1[par0][:,1024:] = h0_layer1
    int b = i >> 10, d = i & 1023;
    xB1[b * 2048 + 1024 + d] = f2bf(h0[65536 + b * 1024 + d]); return;
  }
  i -= 65536;
  if (i < 131072) { cst[i] = c0[i]; return; }   // c0s,c1s contiguous
  i -= 131072;
  if (i < 384) bar[i] = 0;   // 256 arrival flags + release word region
}

// ---------------- flag-array grid barrier (no contended RMW) ---------------
// bar[0..255] arrival flags (one word per block); bar[320] release word.
__device__ __forceinline__ void grid_barrier(unsigned int* bar, int bi,
                                             unsigned int gen) {
  __syncthreads();
  if (threadIdx.x < 64) {
    if (threadIdx.x == 0) {
      __threadfence();  // release this block's phase writes (agent scope)
      __hip_atomic_store(&bar[bi], gen, __ATOMIC_RELEASE, __HIP_MEMORY_SCOPE_AGENT);
    }
    if (bi == 0) {
      const int l = threadIdx.x;
      for (;;) {
        unsigned int v0 = __hip_atomic_load(&bar[l * 4 + 0], __ATOMIC_RELAXED, __HIP_MEMORY_SCOPE_AGENT);
        unsigned int v1 = __hip_atomic_load(&bar[l * 4 + 1], __ATOMIC_RELAXED, __HIP_MEMORY_SCOPE_AGENT);
        unsigned int v2 = __hip_atomic_load(&bar[l * 4 + 2], __ATOMIC_RELAXED, __HIP_MEMORY_SCOPE_AGENT);
        unsigned int v3 = __hip_atomic_load(&bar[l * 4 + 3], __ATOMIC_RELAXED, __HIP_MEMORY_SCOPE_AGENT);
        if (__all(v0 >= gen && v1 >= gen && v2 >= gen && v3 >= gen)) break;
        __builtin_amdgcn_s_sleep(1);
      }
      if (threadIdx.x == 0) {
        __threadfence();
        __hip_atomic_store(&bar[320], gen, __ATOMIC_RELEASE, __HIP_MEMORY_SCOPE_AGENT);
      }
    }
    if (threadIdx.x == 0) {
      while (__hip_atomic_load(&bar[320], __ATOMIC_ACQUIRE,
                               __HIP_MEMORY_SCOPE_AGENT) < gen)
        __builtin_amdgcn_s_sleep(1);
      __threadfence();  // acquire side: see other blocks' writes
    }
  }
  __syncthreads();
}

// ---------------- LSTM phase: block bi = 16 weight rows (4 d x 4 gates) ----
// M=64 (waves split M), N=16, K; weights fetched once per step chip-wide.
__device__ __forceinline__ void lstm_phase(
    const u16* __restrict__ X, int K, const u16* __restrict__ W,
    const float* __restrict__ bq, float* __restrict__ cst,
    u16* __restrict__ hA, int hAs, int hAoff,
    u16* __restrict__ hB, int hBs, int hBoff,
    float* __restrict__ hf, int bi, int tid, float* smem)
{
  const int w = tid >> 6, lane = tid & 63, quad = lane >> 4, cL = lane & 15;
  const u16* ap = X + (size_t)(w * 16 + cL) * K + quad * 8;   // A rows: wave's 16 b
  const u16* bp = W + ((size_t)bi * 16 + cL) * K + quad * 8;  // B rows: block's 16
  f32x4 acc0 = {0,0,0,0}, acc1 = {0,0,0,0};
  #pragma unroll 4
  for (int kc = 0; kc < K; kc += 64) {
    bf16x8 a0 = *(const bf16x8*)ap;
    bf16x8 b0 = *(const bf16x8*)bp;
    bf16x8 a1 = *(const bf16x8*)(ap + 32);
    bf16x8 b1 = *(const bf16x8*)(bp + 32);
    ap += 64; bp += 64;
    acc0 = __builtin_amdgcn_mfma_f32_16x16x32_bf16(a0, b0, acc0, 0, 0, 0);
    acc1 = __builtin_amdgcn_mfma_f32_16x16x32_bf16(a1, b1, acc1, 0, 0, 0);
  }
  // C tile: row m = quad*4+r (b within wave), col = cL (weight row within block)
  #pragma unroll
  for (int r = 0; r < 4; ++r)
    smem[(w * 16 + quad * 4 + r) * 17 + cL] = acc0[r] + acc1[r];
  __syncthreads();
  // pointwise: thread -> (b, dd); gates at cols dd*4 + {0,1,2,3}
  const int b = tid >> 2, dd = tid & 3;
  const float* gp = smem + b * 17 + dd * 4;
  const int rbase = bi * 16 + dd * 4;
  const float gi = gp[0] + bq[rbase + 0];
  const float gf = gp[1] + bq[rbase + 1];
  const float gg = gp[2] + bq[rbase + 2];
  const float go = gp[3] + bq[rbase + 3];
  const int d = bi * 4 + dd;
  const size_t ci = (size_t)b * 1024 + d;
  const float cn = sigmoidf_(gf) * cst[ci] + sigmoidf_(gi) * tanhf(gg);
  const float h  = sigmoidf_(go) * tanhf(cn);
  cst[ci] = cn;
  const u16 hb = f2bf(h);
  hA[(size_t)b * hAs + hAoff + d] = hb;
  if (hB) hB[(size_t)b * hBs + hBoff + d] = hb;
  if (hf) hf[ci] = h;
}

// ---------------- C part 1: scores + softmax for one b ---------------------
__device__ __forceinline__ void scores_softmax(
    int b, const float* __restrict__ h1f, const u16* __restrict__ ctx2,
    float* __restrict__ alignG, float* __restrict__ attnOut, int tid, float* smem)
{
  float* h1s = smem;          // [1024]
  float* red = smem + 1024;   // [256]
  for (int i = tid; i < 1024; i += 256) h1s[i] = h1f[(size_t)b * 1024 + i];
  __syncthreads();
  {
    const int s = tid >> 2, pq = tid & 3;
    const u16* crow = ctx2 + (size_t)(s * 64 + b) * 1024 + pq * 256;
    const float* hp = h1s + pq * 256;
    float part = 0.f;
    #pragma unroll 8
    for (int e = 0; e < 256; e += 4) {
      ushort4 cc = *(const ushort4*)(crow + e);
      part += hp[e] * bf2f(cc.x) + hp[e + 1] * bf2f(cc.y)
            + hp[e + 2] * bf2f(cc.z) + hp[e + 3] * bf2f(cc.w);
    }
    red[tid] = part;
  }
  __syncthreads();
  if (tid < 64) {
    float sc = red[tid * 4] + red[tid * 4 + 1] + red[tid * 4 + 2] + red[tid * 4 + 3];
    float mx = sc;
    for (int off = 32; off; off >>= 1) mx = fmaxf(mx, __shfl_xor(mx, off, 64));
    const float ex = expf(sc - mx);
    float sm = ex;
    for (int off = 32; off; off >>= 1) sm += __shfl_xor(sm, off, 64);
    const float a = ex / sm;
    alignG[b * 64 + tid] = a;
    attnOut[b * 64 + tid] = a;
  }
}

// ---------------- C part 2: qh = h1 · WoutH^T (one 16-col group) -----------
__device__ __forceinline__ void qh_gemm(
    int cg, const u16* __restrict__ h1, const u16* __restrict__ WH,
    float* __restrict__ qh, int tid)
{
  const int w = tid >> 6, lane = tid & 63, quad = lane >> 4, cL = lane & 15;
  const u16* ap = h1 + (size_t)(w * 16 + cL) * 2048 + quad * 8;
  const u16* bp = WH + (size_t)(cg * 16 + cL) * 1024 + quad * 8;
  f32x4 a0 = {0,0,0,0}, a1 = {0,0,0,0};
  #pragma unroll 4
  for (int kc = 0; kc < 1024; kc += 64) {
    bf16x8 av0 = *(const bf16x8*)ap;
    bf16x8 bv0 = *(const bf16x8*)bp;
    bf16x8 av1 = *(const bf16x8*)(ap + 32);
    bf16x8 bv1 = *(const bf16x8*)(bp + 32);
    ap += 64; bp += 64;
    a0 = __builtin_amdgcn_mfma_f32_16x16x32_bf16(av0, bv0, a0, 0, 0, 0);
    a1 = __builtin_amdgcn_mfma_f32_16x16x32_bf16(av1, bv1, a1, 0, 0, 0);
  }
  #pragma unroll
  for (int r = 0; r < 4; ++r)
    qh[(size_t)(w * 16 + quad * 4 + r) * 1024 + cg * 16 + cL] = a0[r] + a1[r];
}

// ---------------- D: attn_h = tanh(qh + sum_s align*ctx3) ------------------
__device__ __forceinline__ void dprime(
    int bi, int tid, const float* __restrict__ qh, const float* __restrict__ alignG,
    const u16* __restrict__ ctx3, float* __restrict__ outT, u16* __restrict__ xAn,
    const float* __restrict__ embNext, float* smem)
{
  const int b = bi >> 2, dc = bi & 3;
  const int d = dc * 256 + tid;
  if (tid < 64) smem[tid] = alignG[b * 64 + tid];
  __syncthreads();
  float acc = qh[(size_t)b * 1024 + d];
  const u16* cp = ctx3 + (size_t)b * 1024 + d;
  #pragma unroll 8
  for (int s = 0; s < 64; ++s)
    acc += smem[s] * bf2f(cp[(size_t)s * 65536]);
  const float v = tanhf(acc);
  outT[(size_t)b * 1024 + d] = v;
  xAn[(size_t)b * 3072 + d] = f2bf(v);
  if (embNext) xAn[(size_t)b * 3072 + 1024 + d] = f2bf(embNext[(size_t)b * 1024 + d]);
}

// ---------------- the persistent kernel ------------------------------------
__global__ __launch_bounds__(256, 1) void k_persist(
    const u16* __restrict__ Wg0q, const u16* __restrict__ Wg1q,
    const u16* __restrict__ WoutHb, const u16* __restrict__ ctx2,
    const u16* __restrict__ ctx3, const float* __restrict__ b0q,
    const float* __restrict__ b1q, const float* __restrict__ emb,
    u16* __restrict__ xA, u16* __restrict__ xB1, float* __restrict__ h1f,
    float* __restrict__ c0s, float* __restrict__ c1s, float* __restrict__ qh,
    float* __restrict__ alignG, unsigned int* __restrict__ bar,
    float* __restrict__ out, float* __restrict__ outA)
{
  const int bi = blockIdx.x, tid = threadIdx.x;
  __shared__ float smem[1280];
  unsigned int gen = 0;
  for (int t = 0; t < 64; ++t) {
    const int p = t & 1;
    u16* xAp = xA + (size_t)p * 196608;
    u16* xAn = xA + (size_t)(1 - p) * 196608;
    u16* xBp = xB1 + (size_t)p * 131072;
    u16* xBn = xB1 + (size_t)(1 - p) * 131072;
    // A: lstm0 -> h_0 into xB[p][:, :1024] and xA[1-p][:, 2048:]
    lstm_phase(xAp, 3072, Wg0q, b0q, c0s,
               xBp, 2048, 0, xAn, 3072, 2048, nullptr, bi, tid, smem);
    grid_barrier(bar, bi, ++gen);
    // B: lstm1 -> h1 into xB[1-p][:, 1024:] and h1f (fp32)
    lstm_phase(xBp, 2048, Wg1q, b1q, c1s,
               xBn, 2048, 1024, (u16*)nullptr, 0, 0, h1f, bi, tid, smem);
    grid_barrier(bar, bi, ++gen);
    // C: scores+softmax (blocks 0-63) | qh GEMM (blocks 64-127)
    if (bi < 64)
      scores_softmax(bi, h1f, ctx2, alignG, outA + (size_t)t * 4096, tid, smem);
    else if (bi < 128)
      qh_gemm(bi - 64, xBn + 1024, WoutHb, qh, tid);
    grid_barrier(bar, bi, ++gen);
    // D: attn_h + stage next x
    dprime(bi, tid, qh, alignG, ctx3, out + (size_t)t * 65536, xAn,
           (t < 63) ? (emb + (size_t)(t + 1) * 65536) : (const float*)nullptr, smem);
    grid_barrier(bar, bi, ++gen);
  }
}

extern "C" void kernel_launch(void* const* d_in, const int* in_sizes, int n_in,
                              void* d_out, int out_size, void* d_ws, size_t ws_size,
                              hipStream_t stream)
{
  const float* emb   = (const float*)d_in[0];
  const float* ctx   = (const float*)d_in[1];
  const float* feed0 = (const float*)d_in[2];
  const float* h0    = (const float*)d_in[3];
  const float* c0    = (const float*)d_in[4];
  const float* Wih0  = (const float*)d_in[5];
  const float* Whh0  = (const float*)d_in[6];
  const float* bih0  = (const float*)d_in[7];
  const float* bhh0  = (const float*)d_in[8];
  const float* Wih1  = (const float*)d_in[9];
  const float* Whh1  = (const float*)d_in[10];
  const float* bih1  = (const float*)d_in[11];
  const float* bhh1  = (const float*)d_in[12];
  const float* Win   = (const float*)d_in[13];
  const float* WoutW = (const float*)d_in[14];
  float* out = (float*)d_out;

  char* w = (char*)d_ws;
  u16*   Wg0q   = (u16*)(w + 0);            // 4096x3072 bf16 (rows d*4+g)
  u16*   Wg1q   = (u16*)(w + 25165824);     // 4096x2048
  u16*   WoutCb = (u16*)(w + 41943040);     // 1024x1024
  u16*   WoutHb = (u16*)(w + 44040192);     // 1024x1024
  u16*   WinT   = (u16*)(w + 46137344);     // 1024x1024
  u16*   ctxb   = (u16*)(w + 48234496);     // 4096x1024
  u16*   ctx2   = (u16*)(w + 56623104);     // 4096x1024
  u16*   ctx3   = (u16*)(w + 65011712);     // 4096x1024
  u16*   xA     = (u16*)(w + 73400320);     // 2 x 64x3072
  u16*   xB1    = (u16*)(w + 74186752);     // 2 x 64x2048
  float* h1f    = (float*)(w + 74711040);   // 64x1024
  float* c0s    = (float*)(w + 74973184);   // 64x1024
  float* c1s    = (float*)(w + 75235328);   // 64x1024 (contiguous after c0s)
  float* qh     = (float*)(w + 75497472);   // 64x1024
  float* alignG = (float*)(w + 75759616);   // 64x64
  float* b0q    = (float*)(w + 75776000);   // 4096
  float* b1q    = (float*)(w + 75792384);   // 4096
  unsigned int* bar = (unsigned int*)(w + 75808768);  // 384 words

  k_prep<<<110624, 256, 0, stream>>>(Wih0, Whh0, Wih1, Whh1, WoutW, Win, ctx,
                                     bih0, bhh0, bih1, bhh1,
                                     Wg0q, Wg1q, WoutCb, WoutHb, WinT, ctxb,
                                     b0q, b1q);
  k_gemm1k<<<dim3(16, 64), 256, 0, stream>>>(ctxb, WinT, ctx2);
  k_gemm1k<<<dim3(16, 64), 256, 0, stream>>>(ctxb, WoutCb, ctx3);
  k_init<<<1538, 256, 0, stream>>>(emb, feed0, h0, c0, xA, xB1, c0s, bar);

  k_persist<<<256, 256, 0, stream>>>(Wg0q, Wg1q, WoutHb, ctx2, ctx3,
                                     b0q, b1q, emb,
                                     xA, xB1, h1f, c0s, c1s, qh, alignG, bar,
                                     out, out + 4194304);
}